// Round 4
// baseline (570.751 us; speedup 1.0000x reference)
//
#include <hip/hip_runtime.h>
#include <stdint.h>
#include <stddef.h>

// ---------- types ----------
typedef __attribute__((ext_vector_type(8))) short bf16x8;
typedef __attribute__((ext_vector_type(4))) short s16x4;
typedef __attribute__((ext_vector_type(4))) float f32x4;

__device__ __forceinline__ short f2bf(float x) {
  uint32_t u = __builtin_bit_cast(uint32_t, x);
  u += 0x7fffu + ((u >> 16) & 1u);
  return (short)(u >> 16);
}

// async global->LDS, 16B per lane; LDS dest = wave-uniform base + lane*16
__device__ __forceinline__ void gload16(const short* g, short* l) {
  __builtin_amdgcn_global_load_lds(
      (const __attribute__((address_space(1))) void*)g,
      (__attribute__((address_space(3))) void*)l, 16, 0, 0);
}

// ---------- problem constants ----------
// B=16 N=512 H=768 G=8 D=96 L=16 LD=1536
#define PB 16
#define PN 512
#define PH 768
#define PG 8
#define PD 96
#define PL 16
#define PLD 1536
#define PC 3072   // qkv concat cols

// ---------- K0a: transpose + convert weights to bf16 ----------
__global__ void transpose_bf16_k(const float* __restrict__ src, short* __restrict__ dst,
                                 int R, int C) {
  __shared__ float tile[32][33];
  int c0 = blockIdx.x * 32, r0 = blockIdx.y * 32;
  int tx = threadIdx.x;        // 0..31
  int ty = threadIdx.y;        // 0..7
  for (int i = 0; i < 4; i++) {
    int r = r0 + ty + i * 8;
    tile[ty + i * 8][tx] = src[(size_t)r * C + c0 + tx];
  }
  __syncthreads();
  for (int i = 0; i < 4; i++) {
    int c = c0 + ty + i * 8;
    dst[(size_t)c * R + r0 + tx] = f2bf(tile[tx][ty + i * 8]);
  }
}

// ---------- K0b: convert X fp32 -> bf16 ----------
__global__ __launch_bounds__(256) void convert_bf16_k(const float* __restrict__ src,
                                                      short* __restrict__ dst) {
  int i = (blockIdx.x * 256 + threadIdx.x) * 4;
  float4 v = *(const float4*)(src + i);
  s16x4 o = { f2bf(v.x), f2bf(v.y), f2bf(v.z), f2bf(v.w) };
  *(s16x4*)(dst + i) = o;
}

// ---------- K1: fused QKV GEMM (m97-style) ----------
__global__ __launch_bounds__(256) void gemm_qkv_k(
    const short* __restrict__ Xb, const short* __restrict__ Wt,
    const float* __restrict__ bv, short* __restrict__ Cb) {
  __shared__ short As[128 * 32];
  __shared__ short Bs[128 * 32];
  int n0 = blockIdx.x * 128;
  int m0 = blockIdx.y * 128;
  int tid = threadIdx.x;
  int wave = tid >> 6, lane = tid & 63, quad = lane >> 4, l16 = lane & 15;
  int wm = wave & 1, wn = wave >> 1;

  f32x4 acc[4][4] = {};

  for (int k0 = 0; k0 < PH; k0 += 32) {
#pragma unroll
    for (int t = 0; t < 2; t++) {
      int rb = (wave * 2 + t) * 16;
      gload16(Xb + (size_t)(m0 + rb + (lane >> 2)) * PH + k0 + (lane & 3) * 8,
              &As[rb * 32]);
      gload16(Wt + (size_t)(n0 + rb + (lane >> 2)) * PH + k0 + (lane & 3) * 8,
              &Bs[rb * 32]);
    }
    __syncthreads();
    bf16x8 af[4], bfv[4];
#pragma unroll
    for (int i = 0; i < 4; i++)
      af[i] = *(bf16x8*)&As[(wm * 64 + i * 16 + l16) * 32 + quad * 8];
#pragma unroll
    for (int j = 0; j < 4; j++)
      bfv[j] = *(bf16x8*)&Bs[(wn * 64 + j * 16 + l16) * 32 + quad * 8];
#pragma unroll
    for (int i = 0; i < 4; i++)
#pragma unroll
      for (int j = 0; j < 4; j++)
        acc[i][j] = __builtin_amdgcn_mfma_f32_16x16x32_bf16(af[i], bfv[j], acc[i][j], 0, 0, 0);
    __syncthreads();
  }

  bool isv = (n0 >= 2 * PH);
  float bvr[4] = {0.f, 0.f, 0.f, 0.f};
  if (isv)
#pragma unroll
    for (int j = 0; j < 4; j++)
      bvr[j] = bv[n0 + wn * 64 + j * 16 + l16 - 2 * PH];

#pragma unroll
  for (int i = 0; i < 4; i++) {
    int rowb = m0 + wm * 64 + i * 16 + quad * 4;
#pragma unroll
    for (int j = 0; j < 4; j++) {
      int col = n0 + wn * 64 + j * 16 + l16;
#pragma unroll
      for (int r = 0; r < 4; r++)
        Cb[(size_t)(rowb + r) * PC + col] = f2bf(acc[i][j][r] + bvr[j]);
    }
  }
}

// ---------- K2: V transpose: Cb v-cols (b,n,l*d) -> vbt (b,l,d,m) ----------
__global__ __launch_bounds__(256) void vtrans2_k(const short* __restrict__ Cb,
                                                 short* __restrict__ vbt) {
  __shared__ short tile[32][36];
  int b = blockIdx.z;
  int ld0 = blockIdx.y * 32;
  int n0 = blockIdx.x * 32;
  int t = threadIdx.x;
  int r = t >> 3, c = (t & 7) * 4;
  *(uint2*)&tile[r][c] =
      *(const uint2*)(Cb + ((size_t)(b * PN) + n0 + r) * PC + 2 * PH + ld0 + c);
  __syncthreads();
  s16x4 o = { tile[c + 0][r], tile[c + 1][r], tile[c + 2][r], tile[c + 3][r] };
  *(s16x4*)(vbt + ((size_t)(b * PLD) + ld0 + r) * PN + n0 + c) = o;
}

// ---------- K3: FUSED scores + eps + G->L proj + mish + softmax + PV ----------
// grid: (32 n-tiles of 16, B). block = 256 (4 waves).
// Pipelined: eps(t+1) prefetched during tile t; 2 barriers/tile (separate sbuf/pbuf).
#define SB_STR 68   // sbuf float stride per n-row
#define PB_STR 72   // pbuf short stride per n-row
__global__ __launch_bounds__(256, 2) void fused_attn_k(
    const short* __restrict__ Cb, const float* __restrict__ eps,
    const float* __restrict__ ebias, const float* __restrict__ sigma,
    const float* __restrict__ p, const short* __restrict__ vbt,
    short* __restrict__ ob) {
  __shared__ __align__(16) float sb[PG][16 * SB_STR];   // 34816 B
  __shared__ __align__(16) short pb[PL][16 * PB_STR];   // 36864 B
  __shared__ float pLs[PG][PL];
  __shared__ float sg2s[PG];

  int n0 = blockIdx.x * 16;
  int b = blockIdx.y;
  int tid = threadIdx.x;
  int wave = tid >> 6, lane = tid & 63, quad = lane >> 4, l16 = lane & 15;

  if (tid < PG * PL) pLs[tid >> 4][tid & 15] = p[tid];
  if (tid < PG) { float s = sigma[tid]; sg2s[tid] = s * s; }
  __syncthreads();
  float sg2r[PG];
#pragma unroll
  for (int g = 0; g < PG; g++) sg2r[g] = sg2s[g];

  const float scale = 0.03608439182435161f;  // 768^-0.5

  // preload Q fragments for this wave's two groups (rows n0..n0+15)
  bf16x8 aq[2][3];
#pragma unroll
  for (int gg = 0; gg < 2; gg++) {
    int g = wave * 2 + gg;
    const short* qg = Cb + ((size_t)(b * PN) + n0 + l16) * PC + g * PD;
#pragma unroll
    for (int ks = 0; ks < 3; ks++)
      aq[gg][ks] = *(const bf16x8*)(qg + ks * 32 + quad * 8);
  }

  // all-ones B fragment for row-sum MFMA
  bf16x8 onesf;
#pragma unroll
  for (int j = 0; j < 8; j++) onesf[j] = (short)0x3F80;

  f32x4 oacc[4][6] = {};   // [li][d-tile]; l = wave*4 + li
  f32x4 sacc[4] = {};      // row sums, same C-layout rows as oacc

  // ---- eps/bias prefetch for tile 0 ----
  float er[4][PG];
  float br[4];
#pragma unroll
  for (int s = 0; s < 4; s++) {
    int n = wave + 4 * s;
#pragma unroll
    for (int g = 0; g < PG; g++)
      er[s][g] = eps[((size_t)(b * PG + g) * PN + n0 + n) * PN + lane];
    br[s] = ebias[((size_t)b * PN + n0 + n) * PN + lane];
  }

  for (int mt = 0; mt < 8; mt++) {
    int m0 = mt * 64;
    // ---- P1: scores for this wave's 2 groups (16n x 64m) -> sbuf ----
#pragma unroll
    for (int gg = 0; gg < 2; gg++) {
      int g = wave * 2 + gg;
      const short* kg = Cb + ((size_t)(b * PN) + m0) * PC + PH + g * PD;
#pragma unroll
      for (int ms = 0; ms < 4; ms++) {
        f32x4 acc = {};
#pragma unroll
        for (int ks = 0; ks < 3; ks++) {
          bf16x8 bk = *(const bf16x8*)(kg + (size_t)(ms * 16 + l16) * PC + ks * 32 + quad * 8);
          acc = __builtin_amdgcn_mfma_f32_16x16x32_bf16(aq[gg][ks], bk, acc, 0, 0, 0);
        }
#pragma unroll
        for (int r = 0; r < 4; r++)
          sb[g][(quad * 4 + r) * SB_STR + ms * 16 + l16] = acc[r];
      }
    }
    __syncthreads();   // B1: sbuf readable
    // ---- P2a: consume sbuf + er into sv (float2-packed over s-pairs) ----
    float2 sv[2][PG];
#pragma unroll
    for (int sp = 0; sp < 2; sp++) {
      int na = wave + 4 * (2 * sp), nb_ = wave + 4 * (2 * sp + 1);
#pragma unroll
      for (int g = 0; g < PG; g++) {
        sv[sp][g].x = sb[g][na * SB_STR + lane] + sg2r[g] * er[2 * sp][g];
        sv[sp][g].y = sb[g][nb_ * SB_STR + lane] + sg2r[g] * er[2 * sp + 1][g];
      }
    }
    float bias2[2][2] = {{br[0], br[1]}, {br[2], br[3]}};
    // ---- prefetch eps/bias for tile t+1 (clamped; hidden under P2b+P3+P1) ----
    {
      int m0n = (mt < 7) ? (m0 + 64) : m0;
#pragma unroll
      for (int s = 0; s < 4; s++) {
        int n = wave + 4 * s;
#pragma unroll
        for (int g = 0; g < PG; g++)
          er[s][g] = eps[((size_t)(b * PG + g) * PN + n0 + n) * PN + m0n + lane];
        br[s] = ebias[((size_t)b * PN + n0 + n) * PN + m0n + lane];
      }
    }
    // ---- P2b: proj (packed) + mish + exp -> pbuf ----
    for (int l = 0; l < PL; l++) {
      float2 a2[2] = {{0.f, 0.f}, {0.f, 0.f}};
#pragma unroll
      for (int g = 0; g < PG; g++) {
        float pv = pLs[g][l];
        a2[0].x += sv[0][g].x * pv; a2[0].y += sv[0][g].y * pv;
        a2[1].x += sv[1][g].x * pv; a2[1].y += sv[1][g].y * pv;
      }
#pragma unroll
      for (int sp = 0; sp < 2; sp++) {
#pragma unroll
        for (int h = 0; h < 2; h++) {
          float a = h ? a2[sp].y : a2[sp].x;
          float ex = __expf(a);
          float t = 1.f + ex;
          float r2 = t * t;
          float mi = (a > 20.f) ? a : a * (r2 - 1.f) * __builtin_amdgcn_rcpf(r2 + 1.f);
          float e = __expf(mi * scale + bias2[sp][h]);
          pb[l][(wave + 4 * (2 * sp + h)) * PB_STR + lane] = f2bf(e);
        }
      }
    }
    __syncthreads();   // B2: pbuf readable
    // ---- P3: PV + rowsum MFMA; wave handles l = wave*4 + li ----
#pragma unroll
    for (int li = 0; li < 4; li++) {
      int l = wave * 4 + li;
      bf16x8 af0 = *(bf16x8*)&pb[l][l16 * PB_STR + 0 + quad * 8];
      bf16x8 af1 = *(bf16x8*)&pb[l][l16 * PB_STR + 32 + quad * 8];
      const short* vb = vbt + ((size_t)(b * PL + l) * PD) * PN + m0;
#pragma unroll
      for (int dt = 0; dt < 6; dt++) {
        bf16x8 b0 = *(const bf16x8*)(vb + (size_t)(dt * 16 + l16) * PN + quad * 8);
        bf16x8 b1 = *(const bf16x8*)(vb + (size_t)(dt * 16 + l16) * PN + 32 + quad * 8);
        oacc[li][dt] = __builtin_amdgcn_mfma_f32_16x16x32_bf16(af0, b0, oacc[li][dt], 0, 0, 0);
        oacc[li][dt] = __builtin_amdgcn_mfma_f32_16x16x32_bf16(af1, b1, oacc[li][dt], 0, 0, 0);
      }
      sacc[li] = __builtin_amdgcn_mfma_f32_16x16x32_bf16(af0, onesf, sacc[li], 0, 0, 0);
      sacc[li] = __builtin_amdgcn_mfma_f32_16x16x32_bf16(af1, onesf, sacc[li], 0, 0, 0);
    }
    // no barrier here: pbuf next written in P2b(t+1), which is after B1(t+1)
  }

  // ---- epilogue: normalize rows and store (b, n, l*96+d) bf16 ----
#pragma unroll
  for (int li = 0; li < 4; li++) {
    int l = wave * 4 + li;
#pragma unroll
    for (int r = 0; r < 4; r++) {
      int n = quad * 4 + r;
      float inv = __builtin_amdgcn_rcpf(sacc[li][r]);
#pragma unroll
      for (int dt = 0; dt < 6; dt++) {
        float o = oacc[li][dt][r] * inv;
        ob[((size_t)(b * PN) + n0 + n) * PLD + l * PD + dt * 16 + l16] = f2bf(o);
      }
    }
  }
}

// ---------- K4: output GEMM (m97-style): out(8192x768 fp32) = ob * Wout^T ----------
__global__ __launch_bounds__(256) void gemm_out_k(
    const short* __restrict__ A, const short* __restrict__ Bt,
    float* __restrict__ out) {
  __shared__ short As[128 * 32];
  __shared__ short Bs[128 * 32];
  int n0 = blockIdx.x * 128;
  int m0 = blockIdx.y * 128;
  int tid = threadIdx.x;
  int wave = tid >> 6, lane = tid & 63, quad = lane >> 4, l16 = lane & 15;
  int wm = wave & 1, wn = wave >> 1;
  f32x4 acc[4][4] = {};
  for (int k0 = 0; k0 < PLD; k0 += 32) {
#pragma unroll
    for (int t = 0; t < 2; t++) {
      int rb = (wave * 2 + t) * 16;
      gload16(A + (size_t)(m0 + rb + (lane >> 2)) * PLD + k0 + (lane & 3) * 8,
              &As[rb * 32]);
      gload16(Bt + (size_t)(n0 + rb + (lane >> 2)) * PLD + k0 + (lane & 3) * 8,
              &Bs[rb * 32]);
    }
    __syncthreads();
    bf16x8 af[4], bfv[4];
#pragma unroll
    for (int i = 0; i < 4; i++)
      af[i] = *(bf16x8*)&As[(wm * 64 + i * 16 + l16) * 32 + quad * 8];
#pragma unroll
    for (int j = 0; j < 4; j++)
      bfv[j] = *(bf16x8*)&Bs[(wn * 64 + j * 16 + l16) * 32 + quad * 8];
#pragma unroll
    for (int i = 0; i < 4; i++)
#pragma unroll
      for (int j = 0; j < 4; j++)
        acc[i][j] = __builtin_amdgcn_mfma_f32_16x16x32_bf16(af[i], bfv[j], acc[i][j], 0, 0, 0);
    __syncthreads();
  }
#pragma unroll
  for (int i = 0; i < 4; i++) {
    int rowb = m0 + wm * 64 + i * 16 + quad * 4;
#pragma unroll
    for (int j = 0; j < 4; j++) {
      int col = n0 + wn * 64 + j * 16 + l16;
#pragma unroll
      for (int r = 0; r < 4; r++)
        out[(size_t)(rowb + r) * PH + col] = acc[i][j][r];
    }
  }
}

// ---------- launcher ----------
extern "C" void kernel_launch(void* const* d_in, const int* in_sizes, int n_in,
                              void* d_out, int out_size, void* d_ws, size_t ws_size,
                              hipStream_t stream) {
  (void)in_sizes; (void)n_in; (void)out_size; (void)ws_size;
  const float* x     = (const float*)d_in[0];
  const float* ebias = (const float*)d_in[1];
  const float* eps   = (const float*)d_in[2];
  const float* Wq    = (const float*)d_in[3];
  const float* Wk    = (const float*)d_in[4];
  const float* Wv    = (const float*)d_in[5];
  const float* bv    = (const float*)d_in[6];
  const float* sigma = (const float*)d_in[7];
  const float* p     = (const float*)d_in[8];
  const float* Wout  = (const float*)d_in[9];
  float* out = (float*)d_out;

  char* ws = (char*)d_ws;
  short* xb     = (short*)(ws + 0);           // 12,582,912 B
  short* wqkv_t = (short*)(ws + 12582912);    //  4,718,592 B
  short* wout_t = (short*)(ws + 17301504);    //  2,359,296 B
  short* Cb     = (short*)(ws + 19660800);    // 50,331,648 B
  short* vbt    = (short*)(ws + 69992448);    // 25,165,824 B
  short* ob     = (short*)(ws + 95158272);    // 25,165,824 B

  dim3 tb(32, 8);
  transpose_bf16_k<<<dim3(24, 24), tb, 0, stream>>>(Wq, wqkv_t, PH, PH);
  transpose_bf16_k<<<dim3(24, 24), tb, 0, stream>>>(Wk, wqkv_t + 768 * 768, PH, PH);
  transpose_bf16_k<<<dim3(48, 24), tb, 0, stream>>>(Wv, wqkv_t + 1536 * 768, PH, PLD);
  transpose_bf16_k<<<dim3(24, 48), tb, 0, stream>>>(Wout, wout_t, PLD, PH);
  convert_bf16_k<<<dim3(6144), 256, 0, stream>>>(x, xb);

  gemm_qkv_k<<<dim3(24, 64), 256, 0, stream>>>(xb, wqkv_t, bv, Cb);
  vtrans2_k<<<dim3(16, 48, 16), 256, 0, stream>>>(Cb, vbt);
  fused_attn_k<<<dim3(32, 16), 256, 0, stream>>>(Cb, eps, ebias, sigma, p, vbt, ob);
  gemm_out_k<<<dim3(6, 64), 256, 0, stream>>>(ob, wout_t, out);
}